// Round 6
// baseline (491.472 us; speedup 1.0000x reference)
//
#include <hip/hip_runtime.h>
#include <stdint.h>

// PairDistanceLoss: loss_i = (sum_{y=1} exp(x)) * (sum_{y=0} exp(-x)) / (ni*(C-ni))
// output = mean_i loss_i (fp32 scalar). N=16384 rows, C=4096 cols.
//
// R5 post-mortem: L2-bypass (sc0 sc1 nt) NEUTRAL at ~3.9 TB/s read. Fill does
// 6.7 TB/s (write, no return path) -> the read cap is in the CU's load-return
// tracking, not the fabric. R6: split the stream across the two independent
// return paths: x via nt vector loads (VGPR return), y via global_load_lds
// DMA (LDS return). y's staged reads are asm ds_read_b128 inside the same asm
// block as the manual vmcnt wait, so the compiler's conservative LDS-DMA
// hazard pass can't insert a serializing vmcnt(0).

typedef float    v4f __attribute__((ext_vector_type(4)));
typedef unsigned v4u __attribute__((ext_vector_type(4)));

#define C_DIM 4096
#define BLOCK 256
#define WPB   4      // waves per block
#define NBLK  4096   // 1 row per wave

typedef __attribute__((address_space(1))) const void gvoid;
typedef __attribute__((address_space(3))) void lvoid;

__global__ __launch_bounds__(BLOCK) void pdl_rows(const float* __restrict__ x,
                                                  const int* __restrict__ y,
                                                  float* __restrict__ partial) {
    // 4 slots/wave, each 2 KB (2 parts x 64 lanes x 16 B) -> 32 KB/block
    __shared__ v4u yslots[WPB][4][2][64];
    __shared__ float sacc[WPB];

    const int lane = threadIdx.x & 63;
    const int wave = threadIdx.x >> 6;
    const int row  = blockIdx.x * WPB + wave;

    const v4f* xp = (const v4f*)(x + (size_t)row * C_DIM) + lane;
    const v4u* yp = (const v4u*)(y + (size_t)row * C_DIM) + lane;

    // LDS byte offset of this wave's slot region, per-lane read address
    const unsigned lds_rd =
        (unsigned)(size_t)(__attribute__((address_space(3))) char*)&yslots[wave][0][0][0]
        + (unsigned)lane * 16u;

    v4f xs0[4], xs1[4];   // rotating x chunk buffers (slot-indexed)
    float pos = 0.0f, neg = 0.0f;
    int cnt = 0;

    // issue chunk c into slot s: 2 nt x-loads (VGPR path) + 2 LDS-DMAs (LDS path)
#define ISSUE(s, c)                                                           \
    do {                                                                      \
        const v4f* pa0 = xp + ((c) * 2 + 0) * 64;                             \
        const v4f* pa1 = xp + ((c) * 2 + 1) * 64;                             \
        asm volatile("global_load_dwordx4 %0, %1, off nt"                     \
                     : "=v"(xs0[s]) : "v"(pa0) : "memory");                   \
        asm volatile("global_load_dwordx4 %0, %1, off nt"                     \
                     : "=v"(xs1[s]) : "v"(pa1) : "memory");                   \
        __builtin_amdgcn_global_load_lds((gvoid*)(yp + ((c) * 2 + 0) * 64),   \
                                         (lvoid*)&yslots[wave][s][0][0],      \
                                         16, 0, 0);                           \
        __builtin_amdgcn_global_load_lds((gvoid*)(yp + ((c) * 2 + 1) * 64),   \
                                         (lvoid*)&yslots[wave][s][1][0],      \
                                         16, 0, 0);                           \
    } while (0)

    // wait for chunk in slot s (vmcnt<=N), read its staged y from LDS;
    // x regs tethered so their uses can't be scheduled above the wait.
#define CONSUME(s, N, yv0, yv1)                                               \
    asm volatile("s_waitcnt vmcnt(" #N ")\n\t"                                \
                 "ds_read_b128 %0, %4 offset:0\n\t"                           \
                 "ds_read_b128 %1, %4 offset:1024\n\t"                        \
                 "s_waitcnt lgkmcnt(0)"                                       \
                 : "=&v"(yv0), "=&v"(yv1), "+v"(xs0[s]), "+v"(xs1[s])         \
                 : "v"(lds_rd + (s) * 2048u) : "memory")

#define COMPUTE(t0, t1, yv0, yv1)                                             \
    do {                                                                      \
        _Pragma("unroll")                                                     \
        for (int e = 0; e < 4; ++e) {                                         \
            { const unsigned yy = yv0[e]; const float xx = t0[e];             \
              const float ex = __expf(yy ? xx : -xx);                         \
              pos += yy ? ex : 0.0f; neg += yy ? 0.0f : ex; cnt += (int)yy; } \
            { const unsigned yy = yv1[e]; const float xx = t1[e];             \
              const float ex = __expf(yy ? xx : -xx);                         \
              pos += yy ? ex : 0.0f; neg += yy ? 0.0f : ex; cnt += (int)yy; } \
        }                                                                     \
    } while (0)

#define ITER_ISSUE(c, s, N)                                                   \
    do {                                                                      \
        v4u yv0, yv1;                                                         \
        CONSUME(s, N, yv0, yv1);                                              \
        const v4f t0 = xs0[s], t1 = xs1[s];                                   \
        ISSUE(s, (c) + 4);                                                    \
        COMPUTE(t0, t1, yv0, yv1);                                            \
    } while (0)

#define ITER_TAIL(c, s, N)                                                    \
    do {                                                                      \
        v4u yv0, yv1;                                                         \
        CONSUME(s, N, yv0, yv1);                                              \
        const v4f t0 = xs0[s], t1 = xs1[s];                                   \
        COMPUTE(t0, t1, yv0, yv1);                                            \
    } while (0)

    // prologue: 4 chunks (16 VMEM) in flight
    ISSUE(0, 0); ISSUE(1, 1); ISSUE(2, 2); ISSUE(3, 3);

    ITER_ISSUE(0, 0, 12);
    ITER_ISSUE(1, 1, 12);
    ITER_ISSUE(2, 2, 12);
    ITER_ISSUE(3, 3, 12);
    ITER_TAIL (4, 0, 12);
    ITER_TAIL (5, 1, 8);
    ITER_TAIL (6, 2, 4);
    ITER_TAIL (7, 3, 0);

    // wave-64 reduction: lane 0 ends with the row totals
#pragma unroll
    for (int off = 32; off >= 1; off >>= 1) {
        pos += __shfl_down(pos, off, 64);
        neg += __shfl_down(neg, off, 64);
        cnt += __shfl_down(cnt, off, 64);
    }

    if (lane == 0) {
        const float denom = (float)cnt * (float)(C_DIM - cnt);
        sacc[wave] = (pos * neg) / denom;
    }
    __syncthreads();
    if (threadIdx.x == 0) {
        float b = 0.0f;
#pragma unroll
        for (int w = 0; w < WPB; ++w) b += sacc[w];
        partial[blockIdx.x] = b;
    }
}

__global__ __launch_bounds__(BLOCK) void pdl_reduce(const float* __restrict__ partial,
                                                    float* __restrict__ out,
                                                    int n_partial, float inv_n) {
    const float4* p4 = (const float4*)partial;
    float s = 0.0f;
    for (int i = threadIdx.x; i < n_partial / 4; i += BLOCK) {
        const float4 v = p4[i];
        s += (v.x + v.y) + (v.z + v.w);
    }
#pragma unroll
    for (int off = 32; off >= 1; off >>= 1) s += __shfl_down(s, off, 64);
    __shared__ float sw[BLOCK / 64];
    const int lane = threadIdx.x & 63;
    const int wave = threadIdx.x >> 6;
    if (lane == 0) sw[wave] = s;
    __syncthreads();
    if (threadIdx.x == 0) {
        float t = 0.0f;
#pragma unroll
        for (int w = 0; w < BLOCK / 64; ++w) t += sw[w];
        out[0] = t * inv_n;
    }
}

extern "C" void kernel_launch(void* const* d_in, const int* in_sizes, int n_in,
                              void* d_out, int out_size, void* d_ws, size_t ws_size,
                              hipStream_t stream) {
    const float* x = (const float*)d_in[0];
    const int*   y = (const int*)d_in[1];
    float* out = (float*)d_out;
    float* partial = (float*)d_ws;  // NBLK floats, fully rewritten each call

    const int n_rows = in_sizes[0] / C_DIM;  // 16384

    pdl_rows<<<NBLK, BLOCK, 0, stream>>>(x, y, partial);
    pdl_reduce<<<1, BLOCK, 0, stream>>>(partial, out, NBLK, 1.0f / (float)n_rows);
}

// Round 7
// 463.764 us; speedup vs baseline: 1.0597x; 1.0597x over previous
//
#include <hip/hip_runtime.h>

// PairDistanceLoss: loss_i = (sum_{y=1} exp(x)) * (sum_{y=0} exp(-x)) / (ni*(C-ni))
// output = mean_i loss_i (fp32 scalar). N=16384 rows, C=4096 cols.
//
// FINAL (revert to R4 best): nontemporal float4/int4 loads (L1 bypass) with a
// 3-deep register pipeline, one row per wave, block partials -> d_ws -> tiny
// reduce kernel. Kernel ~136us = 536 MB / 3.94 TB/s combined read (x from
// HBM, y from L3) = the chip's demonstrated read-return ceiling.
// Evidence chain: atomics serialized (R1, 230us); MLP batching 162us (R2);
// SW pipeline neutral (R3); nt loads 136us (R4); L2-bypass neutral (R5);
// LDS-DMA dual-path regressed (R6) -> read cap is shared tracking, roofline.

typedef float v4f __attribute__((ext_vector_type(4)));
typedef int   v4i __attribute__((ext_vector_type(4)));

#define C_DIM 4096
#define BLOCK 256
#define NBLK  2048
#define WPB   (BLOCK / 64)       // 4 waves per block
#define RPW   2                  // rows per wave: 16384 / (2048*4)

__global__ __launch_bounds__(BLOCK) void pdl_rows(const float* __restrict__ x,
                                                  const int* __restrict__ y,
                                                  float* __restrict__ partial) {
    const int lane  = threadIdx.x & 63;
    const int wave  = threadIdx.x >> 6;
    const int gwave = blockIdx.x * WPB + wave;
    const int rbase = gwave * RPW;

    float pos = 0.0f, neg = 0.0f;
    int cnt = 0;
    float wacc = 0.0f;  // lane-0 row results

    v4f xa[4], xb[4];
    v4i ya[4], yb[4];

    // global chunk id c in [0, RPW*4): row = rbase + c/4, intra-row chunk c&3
    auto prefetch = [&](v4f (&xv)[4], v4i (&yv)[4], int c) {
        const size_t rowoff = (size_t)(rbase + (c >> 2)) * C_DIM;
        const v4f* __restrict__ x4 = (const v4f*)(x + rowoff);
        const v4i* __restrict__ y4 = (const v4i*)(y + rowoff);
#pragma unroll
        for (int u = 0; u < 4; ++u) {
            const int i = lane + ((c & 3) * 4 + u) * 64;
            xv[u] = __builtin_nontemporal_load(x4 + i);
            yv[u] = __builtin_nontemporal_load(y4 + i);
        }
    };
    auto compute = [&](const v4f (&xv)[4], const v4i (&yv)[4]) {
#pragma unroll
        for (int u = 0; u < 4; ++u) {
#pragma unroll
            for (int e = 0; e < 4; ++e) {
                const int   yy = yv[u][e];
                const float xx = xv[u][e];
                const float ex = __expf(yy ? xx : -xx);
                pos += yy ? ex : 0.0f;
                neg += yy ? 0.0f : ex;
                cnt += yy;
            }
        }
    };
    auto finish_row = [&]() {
#pragma unroll
        for (int off = 32; off >= 1; off >>= 1) {
            pos += __shfl_down(pos, off, 64);
            neg += __shfl_down(neg, off, 64);
            cnt += __shfl_down(cnt, off, 64);
        }
        if (lane == 0) {
            const float denom = (float)cnt * (float)(C_DIM - cnt);
            wacc += (pos * neg) / denom;
        }
        pos = 0.0f; neg = 0.0f; cnt = 0;
    };

    // sustained 2-deep pipeline across both rows (no drain at row boundary)
    prefetch(xa, ya, 0);
    prefetch(xb, yb, 1);
    compute(xa, ya);  prefetch(xa, ya, 2);
    compute(xb, yb);  prefetch(xb, yb, 3);
    compute(xa, ya);  prefetch(xa, ya, 4);
    compute(xb, yb);  prefetch(xb, yb, 5);
    finish_row();     // row 0 done (chunks 0-3 computed)
    compute(xa, ya);  prefetch(xa, ya, 6);
    compute(xb, yb);  prefetch(xb, yb, 7);
    compute(xa, ya);
    compute(xb, yb);
    finish_row();     // row 1 done

    __shared__ float sacc[WPB];
    if (lane == 0) sacc[wave] = wacc;
    __syncthreads();
    if (threadIdx.x == 0) {
        float b = 0.0f;
#pragma unroll
        for (int w = 0; w < WPB; ++w) b += sacc[w];
        partial[blockIdx.x] = b;
    }
}

__global__ __launch_bounds__(BLOCK) void pdl_reduce(const float* __restrict__ partial,
                                                    float* __restrict__ out,
                                                    int n_partial, float inv_n) {
    const float4* p4 = (const float4*)partial;
    float s = 0.0f;
    for (int i = threadIdx.x; i < n_partial / 4; i += BLOCK) {
        const float4 v = p4[i];
        s += (v.x + v.y) + (v.z + v.w);
    }
#pragma unroll
    for (int off = 32; off >= 1; off >>= 1) s += __shfl_down(s, off, 64);
    __shared__ float sw[BLOCK / 64];
    const int lane = threadIdx.x & 63;
    const int wave = threadIdx.x >> 6;
    if (lane == 0) sw[wave] = s;
    __syncthreads();
    if (threadIdx.x == 0) {
        float t = 0.0f;
#pragma unroll
        for (int w = 0; w < BLOCK / 64; ++w) t += sw[w];
        out[0] = t * inv_n;
    }
}

extern "C" void kernel_launch(void* const* d_in, const int* in_sizes, int n_in,
                              void* d_out, int out_size, void* d_ws, size_t ws_size,
                              hipStream_t stream) {
    const float* x = (const float*)d_in[0];
    const int*   y = (const int*)d_in[1];
    float* out = (float*)d_out;
    float* partial = (float*)d_ws;  // NBLK floats, fully rewritten each call

    const int n_rows = in_sizes[0] / C_DIM;  // 16384

    pdl_rows<<<NBLK, BLOCK, 0, stream>>>(x, y, partial);
    pdl_reduce<<<1, BLOCK, 0, stream>>>(partial, out, NBLK, 1.0f / (float)n_rows);
}